// Round 14
// baseline (239.536 us; speedup 1.0000x reference)
//
#include <hip/hip_runtime.h>
#include <hip/hip_bf16.h>
#include <math.h>

#define T_   2048
#define B_   2
#define E_   1024
#define H_   16
#define D_   64
#define NH_  32
#define M_   4096

typedef __attribute__((ext_vector_type(8))) short s8b;   // 8 bf16 (4 VGPRs)
typedef __attribute__((ext_vector_type(4))) float f4;    // 4 f32 acc

#define MFMA_B16(a,b,c) __builtin_amdgcn_mfma_f32_16x16x32_bf16(a,b,c,0,0,0)
#define LOG2E 1.44269504088896f

__device__ __forceinline__ unsigned short f2bu(float f) {
    union { __hip_bfloat16 h; unsigned short u; } cv;
    cv.h = __float2bfloat16(f);
    return cv.u;
}
// fast bf16: round-half-up truncation (positive finite values) — 2 VALU ops
__device__ __forceinline__ unsigned short f2bu_fast(float f) {
    return (unsigned short)((__float_as_uint(f) + 0x8000u) >> 16);
}
__device__ __forceinline__ float bu2f(unsigned short u) {
    union { __hip_bfloat16 h; unsigned short u; } cv; cv.u = u;
    return __bfloat162float(cv.h);
}
__device__ __forceinline__ unsigned int pk2(float a, float b) {
    return (unsigned int)f2bu(a) | ((unsigned int)f2bu(b) << 16);
}
// pack two f32 -> packed bf16 pair with round-half-up (cheap)
__device__ __forceinline__ unsigned int pk2_fast(float a, float b) {
    return ((__float_as_uint(a) + 0x8000u) >> 16) |
           ((__float_as_uint(b) + 0x8000u) & 0xFFFF0000u);
}
// raw v_exp_f32 — exp2f() without fast-math expands to a denorm-guard
// sequence (~12 extra VALU ops); attention scores never reach denormals.
__device__ __forceinline__ float fexp2(float x) {
    return __builtin_amdgcn_exp2f(x);
}
__device__ __forceinline__ float ld1d(const void* p, size_t idx, bool f32) {
    return f32 ? ((const float*)p)[idx] : bu2f(((const unsigned short*)p)[idx]);
}
// sum across the 4 quads (lane bits 4-5)
__device__ __forceinline__ float qsumq(float v) {
    v += __shfl_xor(v, 16); v += __shfl_xor(v, 32);
    return v;
}
// async global->LDS, 16 B per lane (GEMMs only — attn uses register prefetch
// because its per-tile barrier drains vmcnt(0) and exposes the DMA latency)
__device__ __forceinline__ void glds16(const unsigned short* g, unsigned short* l) {
    __builtin_amdgcn_global_load_lds(
        (const __attribute__((address_space(1))) unsigned int*)g,
        (__attribute__((address_space(3))) unsigned int*)l, 16, 0, 0);
}

// ---------------------------------------------------------------------------
// Input dtype detect (1 = f32 inputs, 0 = bf16 inputs).
// ---------------------------------------------------------------------------
__global__ void detect_dtype(const unsigned short* __restrict__ q, int* __restrict__ flag) {
    int e = (q[threadIdx.x] >> 7) & 0xFF;
    bool sane = (e == 0) || (e >= 97 && e <= 157);
    unsigned long long m = __ballot(sane);
    if (threadIdx.x == 0) *flag = (__popcll(m) >= 56) ? 0 : 1;
}

// ---------------------------------------------------------------------------
// One-pass f32->bf16 conversion of x, Wq..Wo, bq..bo into ws.
// ---------------------------------------------------------------------------
__global__ __launch_bounds__(256) void cvt_bf16(
    const void* __restrict__ x,
    const void* __restrict__ Wq, const void* __restrict__ Wk,
    const void* __restrict__ Wv, const void* __restrict__ Wo,
    const void* __restrict__ bq, const void* __restrict__ bk,
    const void* __restrict__ bv, const void* __restrict__ bo,
    unsigned short* __restrict__ xw, unsigned short* __restrict__ Ww,
    unsigned short* __restrict__ bw, const int* __restrict__ flag)
{
    const bool f32m = (*flag != 0);
    const int y = blockIdx.y;
    const void* src; unsigned short* dst; int n;
    if (y == 0)      { src = x; dst = xw; n = M_ * E_; }
    else if (y <= 4) {
        src = (y == 1) ? Wq : (y == 2) ? Wk : (y == 3) ? Wv : Wo;
        dst = Ww + (size_t)(y - 1) * E_ * E_; n = E_ * E_;
    } else {
        src = (y == 5) ? bq : (y == 6) ? bk : (y == 7) ? bv : bo;
        dst = bw + (size_t)(y - 5) * E_; n = E_;
    }
    int i = (blockIdx.x * 256 + threadIdx.x) * 8;
    if (i >= n) return;
    if (f32m) {
        const float* s = (const float*)src + i;
        float4 f0 = *(const float4*)s, f1 = *(const float4*)(s + 4);
        union { unsigned int d[4]; s8b v; } u;
        u.d[0] = pk2(f0.x, f0.y); u.d[1] = pk2(f0.z, f0.w);
        u.d[2] = pk2(f1.x, f1.y); u.d[3] = pk2(f1.z, f1.w);
        *(s8b*)(dst + i) = u.v;
    } else {
        *(s8b*)(dst + i) = *(const s8b*)((const unsigned short*)src + i);
    }
}

// ---------------------------------------------------------------------------
// QKV projection, bf16 MFMA GEMM, XCD swizzle, glds staging (xor-swizzled),
// double-buffered single-barrier. p==2 (V) is written TRANSPOSED [N][D][T].
// ---------------------------------------------------------------------------
__global__ __launch_bounds__(256, 3) void qkv_gemm(
    const unsigned short* __restrict__ xw, const unsigned short* __restrict__ Ww,
    const unsigned short* __restrict__ bw,
    unsigned short* __restrict__ qo, unsigned short* __restrict__ ko,
    unsigned short* __restrict__ vo)
{
    const int bid = blockIdx.x;            // 768 blocks
    const int r_ = bid & 7, s_ = bid >> 3;
    const int g = r_ + 8 * (s_ >> 3);      // group in [0,96): (m,p)
    const int e0 = (s_ & 7) * 128;
    const int m0 = (g & 31) * 128;
    const int p  = g >> 5;
    const unsigned short* W    = Ww + (size_t)p * E_ * E_;
    const unsigned short* bias = bw + (size_t)p * E_;
    const float scale = (p == 0) ? 0.125f * LOG2E : 1.0f;

    const int tid = threadIdx.x, w = tid >> 6, lane = tid & 63;
    const int quad = lane >> 4, lc = lane & 15;
    const int wx = w & 1, wy = w >> 1;

    __shared__ unsigned short a_s[2][128 * 32];
    __shared__ unsigned short b_s[2][128 * 32];

    f4 acc[4][4];
    #pragma unroll
    for (int i = 0; i < 4; i++)
        #pragma unroll
        for (int j = 0; j < 4; j++) acc[i][j] = (f4){0.f, 0.f, 0.f, 0.f};

    const int gr = lane >> 2;
    const int gc = (lane & 3) ^ ((lane >> 2) & 3);
    const size_t aoff = (size_t)(m0 + w*32 + gr) * E_ + gc*8;
    const size_t boff = (size_t)(e0 + w*32 + gr) * E_ + gc*8;

    #pragma unroll
    for (int j = 0; j < 2; j++) {
        glds16(xw + aoff + (size_t)j*16*E_, &a_s[0][(w*128 + j*64) * 8]);
        glds16(W  + boff + (size_t)j*16*E_, &b_s[0][(w*128 + j*64) * 8]);
    }
    __syncthreads();

    const int fcA = quad ^ (lc & 3);
    for (int k0 = 0; k0 < E_; k0 += 32) {
        const int cur = (k0 >> 5) & 1;
        if (k0 + 32 < E_) {
            #pragma unroll
            for (int j = 0; j < 2; j++) {
                glds16(xw + aoff + (size_t)j*16*E_ + k0 + 32, &a_s[cur^1][(w*128 + j*64) * 8]);
                glds16(W  + boff + (size_t)j*16*E_ + k0 + 32, &b_s[cur^1][(w*128 + j*64) * 8]);
            }
        }
        s8b af[4], bfr[4];
        #pragma unroll
        for (int i = 0; i < 4; i++)
            af[i]  = *(const s8b*)&a_s[cur][((wy*64 + i*16 + lc)*4 + fcA) * 8];
        #pragma unroll
        for (int i = 0; i < 4; i++)
            bfr[i] = *(const s8b*)&b_s[cur][((wx*64 + i*16 + lc)*4 + fcA) * 8];
        #pragma unroll
        for (int ms = 0; ms < 4; ms++)
            #pragma unroll
            for (int ns = 0; ns < 4; ns++)
                acc[ms][ns] = MFMA_B16(af[ms], bfr[ns], acc[ms][ns]);
        __syncthreads();
    }

    float bias_v[4];
    #pragma unroll
    for (int ns = 0; ns < 4; ns++) bias_v[ns] = bu2f(bias[e0 + wx*64 + ns*16 + lc]);

    if (p < 2) {
        #pragma unroll
        for (int ms = 0; ms < 4; ms++)
            #pragma unroll
            for (int ns = 0; ns < 4; ns++)
                #pragma unroll
                for (int r2 = 0; r2 < 4; r2++) {
                    float val = (acc[ms][ns][r2] + bias_v[ns]) * scale;
                    float nb = __shfl_xor(val, 1);
                    if (!(lane & 1)) {
                        int m = m0 + wy*64 + ms*16 + quad*4 + r2;
                        int t = m >> 1, bb = m & 1;
                        int e = e0 + wx*64 + ns*16 + lc;
                        int h = e >> 6, d = e & 63;
                        unsigned short* dst = (p == 0) ? qo : ko;
                        *(unsigned int*)&dst[(((size_t)(bb*H_ + h) * T_ + t) << 6) + d] = pk2(val, nb);
                    }
                }
    } else {
        // V transposed: vo[nh][d][t]
        #pragma unroll
        for (int ms = 0; ms < 4; ms++) {
            int t0v = (m0 + wy*64 + ms*16 + quad*4) >> 1;
            #pragma unroll
            for (int ns = 0; ns < 4; ns++) {
                int e = e0 + wx*64 + ns*16 + lc;
                int h = e >> 6, d = e & 63;
                float v0 = acc[ms][ns][0] + bias_v[ns];
                float v1 = acc[ms][ns][1] + bias_v[ns];
                float v2 = acc[ms][ns][2] + bias_v[ns];
                float v3 = acc[ms][ns][3] + bias_v[ns];
                *(unsigned int*)&vo[((size_t)h        * 64 + d) * T_ + t0v] = pk2(v0, v2);
                *(unsigned int*)&vo[((size_t)(H_ + h) * 64 + d) * T_ + t0v] = pk2(v1, v3);
            }
        }
    }
}

// ---------------------------------------------------------------------------
// Flash attention with Shaw bias — TRANSPOSED-S pipeline + raw v_exp_f32.
// This round: SINGLE-buffered K/V (register prefetch still hides global
// latency; 2 barriers/tile) -> LDS 68.5->52.3 KB -> 3 blocks/CU (12 waves)
// via __launch_bounds__(256,3). Everything else identical to R13.
// ---------------------------------------------------------------------------
__global__ __launch_bounds__(256, 3) void attn_mfma(
    const unsigned short* __restrict__ q, const unsigned short* __restrict__ k,
    const unsigned short* __restrict__ v,
    const void* __restrict__ rk_t, const void* __restrict__ rv_t,
    unsigned short* __restrict__ aout, const int* __restrict__ flag)
{
    const bool f32m = (*flag != 0);
    const int bid = blockIdx.x;
    const int n = bid & 31, qt = bid >> 5;
    const int t0 = qt * 128;
    const int tid = threadIdx.x, w = tid >> 6, lane = tid & 63;
    const int quad = lane >> 4, lc = lane & 15;

    __shared__ unsigned short k_s[64 * 64];      // K[s][d] swizzled (rv^T later)
    __shared__ unsigned short v_s[64 * 64];      // V^T[d][s] swizzled
    __shared__ unsigned short p_s[4][32 * 72];   // per-wave P[t][s] / P_extra; rk staging
    __shared__ unsigned short qrk_s[128 * 36];   // qrk[t_local][r] bf16 (log2 dom.)
    __shared__ unsigned short diag16[128 * 33];  // e-values at |rel|<16, bf16
    __shared__ float st_L[128], st_R[128];

    const unsigned short* qn = q + ((size_t)n * T_ + t0) * D_;
    const unsigned short* kn = k + (size_t)n * T_ * D_;
    const unsigned short* vn = v + (size_t)n * D_ * T_;   // V^T [D][T]

    // Q fragments (B-operand for S^T)
    s8b qa[2][2];
    #pragma unroll
    for (int nt = 0; nt < 2; nt++)
        #pragma unroll
        for (int kf = 0; kf < 2; kf++)
            qa[nt][kf] = *(const s8b*)(qn + (size_t)(w*32 + nt*16 + lc) * D_ + kf*32 + quad*8);

    for (int i = tid; i < 128 * 33; i += 256) diag16[i] = 0;

    // stage rk (bf16, padded [48][72], rows>=33 zero) into p_s area
    unsigned int* rks = (unsigned int*)&p_s[0][0];
    for (int i = tid; i < 48 * 36; i += 256) {
        int r = i / 36, c2 = i % 36;
        unsigned int val = 0;
        if (r < 33 && c2 < 32)
            val = pk2(ld1d(rk_t, r*64 + 2*c2, f32m), ld1d(rk_t, r*64 + 2*c2 + 1, f32m));
        rks[i] = val;
    }
    __syncthreads();

    // qrk[t][r] = q[t] . rk[r] via MFMA (prologue-only)
    #pragma unroll
    for (int mt = 0; mt < 2; mt++)
        for (int nt = 0; nt < 3; nt++) {
            s8b b0 = *(const s8b*)((const unsigned short*)rks + (nt*16 + lc)*72 + quad*8);
            s8b b1 = *(const s8b*)((const unsigned short*)rks + (nt*16 + lc)*72 + 32 + quad*8);
            f4 a = (f4){0.f, 0.f, 0.f, 0.f};
            a = MFMA_B16(qa[mt][0], b0, a);
            a = MFMA_B16(qa[mt][1], b1, a);
            #pragma unroll
            for (int r = 0; r < 4; r++) {
                float nb = __shfl_xor(a[r], 1);
                int col = nt*16 + lc;
                if (!(lane & 1) && col < 34)
                    ((unsigned int*)qrk_s)[(w*32 + mt*16 + quad*4 + r)*18 + (col >> 1)] = pk2(a[r], nb);
            }
        }
    __syncthreads();   // rk staging (aliased with p_s) free after this

    // per-lane Shaw edge biases (t = w*32 + nt*16 + lc)
    float qLn[2], qRn[2];
    float L_p[2] = {0.f, 0.f}, R_p[2] = {0.f, 0.f};
    f4 O[4][2], lsN[2], lsL[2], lsR[2];
    #pragma unroll
    for (int nt = 0; nt < 2; nt++) {
        int row = w*32 + nt*16 + lc;
        qLn[nt] = bu2f(qrk_s[row*36 + 0]);
        qRn[nt] = bu2f(qrk_s[row*36 + 32]);
        lsN[nt] = (f4){0.f, 0.f, 0.f, 0.f};
        lsL[nt] = (f4){0.f, 0.f, 0.f, 0.f};
        lsR[nt] = (f4){0.f, 0.f, 0.f, 0.f};
        #pragma unroll
        for (int dt = 0; dt < 4; dt++) O[dt][nt] = (f4){0.f, 0.f, 0.f, 0.f};
    }
    const short ob = (short)0x3F80;   // bf16 1.0
    const s8b ones = { ob, ob, ob, ob, ob, ob, ob, ob };

    // staging mapping: row group w*16 + j*8 + grr, source chunk xor-swizzled
    const int grr = lane >> 3;
    const int gcc = (lane & 7) ^ grr;
    const size_t koff = (size_t)(w*16 + grr) * D_ + gcc*8;   // + (s0 + j*8)*D_
    const size_t voff = (size_t)(w*16 + grr) * T_ + gcc*8;   // + j*8*T_ + s0

    // tile-0 register prefetch + write buf
    s8b kr0 = *(const s8b*)(kn + koff);
    s8b kr1 = *(const s8b*)(kn + koff + 8*D_);
    s8b vr0 = *(const s8b*)(vn + voff);
    s8b vr1 = *(const s8b*)(vn + voff + (size_t)8*T_);
    *(s8b*)&k_s[(w*128 +      lane) * 8] = kr0;
    *(s8b*)&k_s[(w*128 + 64 + lane) * 8] = kr1;
    *(s8b*)&v_s[(w*128 +      lane) * 8] = vr0;
    *(s8b*)&v_s[(w*128 + 64 + lane) * 8] = vr1;
    __syncthreads();

    const int lc7 = lc & 7;
    for (int kt = 0; kt < 32; kt++) {
        const int s0 = kt * 64;
        if (kt + 1 < 32) {   // issue next tile's global loads now
            kr0 = *(const s8b*)(kn + koff + (size_t)(s0 + 64)*D_);
            kr1 = *(const s8b*)(kn + koff + (size_t)(s0 + 72)*D_);
            vr0 = *(const s8b*)(vn + voff + s0 + 64);
            vr1 = *(const s8b*)(vn + voff + (size_t)8*T_ + s0 + 64);
        }

        const bool farL  = (s0 + 63 < t0 - 16);
        const bool farR  = (s0 > t0 + 143);
        const bool nearT = !farL && !farR;

        // K fragments (A-operand for S^T): K[s=st*16+lc][d]
        s8b ak[4][2];
        #pragma unroll
        for (int st = 0; st < 4; st++) {
            int row = st*16 + lc;
            ak[st][0] = *(const s8b*)&k_s[(row*8 + (quad       ^ lc7)) * 8];
            ak[st][1] = *(const s8b*)&k_s[(row*8 + ((4 + quad) ^ lc7)) * 8];
        }

        // S^T = K·Q^T (+ bias), exp2, pack b64 into P[t][s]
        #pragma unroll
        for (int st = 0; st < 4; st++)
            #pragma unroll
            for (int nt = 0; nt < 2; nt++) {
                f4 a;
                if (nearT) a = (f4){0.f, 0.f, 0.f, 0.f};
                else {
                    float qb = farL ? qLn[nt] : qRn[nt];
                    a = (f4){qb, qb, qb, qb};
                }
                a = MFMA_B16(ak[st][0], qa[nt][0], a);
                a = MFMA_B16(ak[st][1], qa[nt][1], a);
                unsigned int lo, hi;
                if (nearT) {
                    const int t_l = w*32 + nt*16 + lc;
                    const int sb  = s0 + st*16 + quad*4 - (t0 + t_l);
                    unsigned short eb[4];
                    #pragma unroll
                    for (int r = 0; r < 4; r++) {
                        int rel = sb + r;
                        int rc = rel < -16 ? -16 : (rel > 16 ? 16 : rel);
                        float e = fexp2(a[r] + bu2f(qrk_s[t_l*36 + rc + 16]));
                        eb[r] = f2bu_fast(e);
                        if (rel <= -16)      L_p[nt] += e;
                        else if (rel >= 16)  R_p[nt] += e;
                        else                 diag16[t_l*33 + rel + 15] = eb[r];
                    }
                    lo = (unsigned int)eb[0] | ((unsigned int)eb[1] << 16);
                    hi = (unsigned int)eb[2] | ((unsigned int)eb[3] << 16);
                } else {
                    lo = pk2_fast(fexp2(a[0]), fexp2(a[1]));
                    hi = pk2_fast(fexp2(a[2]), fexp2(a[3]));
                }
                *(uint2*)&p_s[w][(nt*16 + lc)*72 + st*16 + quad*4] = make_uint2(lo, hi);
            }

        // P fragments (B-operand): P[t=lc][s=quad*8+j]
        s8b pb[2][2];
        #pragma unroll
        for (int nt = 0; nt < 2; nt++) {
            pb[nt][0] = *(const s8b*)&p_s[w][(nt*16 + lc)*72 + quad*8];
            pb[nt][1] = *(const s8b*)&p_s[w][(nt*16 + lc)*72 + 32 + quad*8];
        }
        // column sums of P^T (= row sums of P) via ones-MFMA
        if (nearT) {
            #pragma unroll
            for (int nt = 0; nt < 2; nt++) {
                lsN[nt] = MFMA_B16(ones, pb[nt][0], lsN[nt]);
                lsN[nt] = MFMA_B16(ones, pb[nt][1], lsN[nt]);
            }
        } else if (farL) {
            #pragma unroll
            for (int nt = 0; nt < 2; nt++) {
                lsL[nt] = MFMA_B16(ones, pb[nt][0], lsL[nt]);
                lsL[nt] = MFMA_B16(ones, pb[nt][1], lsL[nt]);
            }
        } else {
            #pragma unroll
            for (int nt = 0; nt < 2; nt++) {
                lsR[nt] = MFMA_B16(ones, pb[nt][0], lsR[nt]);
                lsR[nt] = MFMA_B16(ones, pb[nt][1], lsR[nt]);
            }
        }
        // O^T += V^T · P^T
        #pragma unroll
        for (int dt = 0; dt < 4; dt++) {
            int row = dt*16 + lc;
            s8b a0 = *(const s8b*)&v_s[(row*8 + (quad       ^ lc7)) * 8];
            s8b a1 = *(const s8b*)&v_s[(row*8 + ((4 + quad) ^ lc7)) * 8];
            O[dt][0] = MFMA_B16(a0, pb[0][0], O[dt][0]);
            O[dt][0] = MFMA_B16(a1, pb[0][1], O[dt][0]);
            O[dt][1] = MFMA_B16(a0, pb[1][0], O[dt][1]);
            O[dt][1] = MFMA_B16(a1, pb[1][1], O[dt][1]);
        }

        __syncthreads();             // all waves done READING k_s/v_s
        if (kt + 1 < 32) {           // overwrite with prefetched tile
            *(s8b*)&k_s[(w*128 +      lane) * 8] = kr0;
            *(s8b*)&k_s[(w*128 + 64 + lane) * 8] = kr1;
            *(s8b*)&v_s[(w*128 +      lane) * 8] = vr0;
            *(s8b*)&v_s[(w*128 + 64 + lane) * 8] = vr1;
        }
        __syncthreads();             // writes visible
    }

    // ---- epilogue: totals, relpos-V via rv^T·P_extra^T, normalize, store ----
    float linv[2];
    #pragma unroll
    for (int nt = 0; nt < 2; nt++) {
        float l = lsN[nt][0] + lsL[nt][0] + lsR[nt][0];
        float L = lsL[nt][0] + qsumq(L_p[nt]);
        float R = lsR[nt][0] + qsumq(R_p[nt]);
        linv[nt] = 1.f / l;
        if (quad == 0) {
            int row = w*32 + nt*16 + lc;
            st_L[row] = L; st_R[row] = R;
        }
    }
    // stage rv TRANSPOSED into k_s with the SAME xor swizzle (r>=33 zero)
    {
        unsigned int* rvs = (unsigned int*)&k_s[0];
        for (int i = tid; i < 64 * 32; i += 256) {
            int d = i >> 5, dwL = i & 31;
            int r0 = dwL * 2, r1 = r0 + 1;
            float x0 = (r0 < 33) ? ld1d(rv_t, (size_t)r0 * 64 + d, f32m) : 0.f;
            float x1 = (r1 < 33) ? ld1d(rv_t, (size_t)r1 * 64 + d, f32m) : 0.f;
            int phys = d * 32 + ((dwL >> 2) ^ (d & 7)) * 4 + (dwL & 3);
            rvs[phys] = pk2(x0, x1);
        }
    }
    __syncthreads();
    // build P_extra[32][64] bf16 in own wave region (cols 33..63 = 0)
    for (int j = 0; j < 32; j++) {
        int c = lane;
        int row = w*32 + j;
        unsigned short pv;
        if (c == 0)        pv = f2bu(st_L[row]);
        else if (c == 32)  pv = f2bu(st_R[row]);
        else if (c < 32)   pv = diag16[row*33 + c - 1];
        else               pv = 0;
        p_s[w][j*72 + c] = pv;
    }
    // O^T += rv^T · P_extra^T
    s8b pe[2][2];
    #pragma unroll
    for (int nt = 0; nt < 2; nt++) {
        pe[nt][0] = *(const s8b*)&p_s[w][(nt*16 + lc)*72 + quad*8];
        pe[nt][1] = *(const s8b*)&p_s[w][(nt*16 + lc)*72 + 32 + quad*8];
    }
    #pragma unroll
    for (int dt = 0; dt < 4; dt++) {
        int row = dt*16 + lc;
        s8b a0 = *(const s8b*)&k_s[(row*8 + (quad       ^ lc7)) * 8];
        s8b a1 = *(const s8b*)&k_s[(row*8 + ((4 + quad) ^ lc7)) * 8];
        O[dt][0] = MFMA_B16(a0, pe[0][0], O[dt][0]);
        O[dt][0] = MFMA_B16(a1, pe[0][1], O[dt][0]);
        O[dt][1] = MFMA_B16(a0, pe[1][0], O[dt][1]);
        O[dt][1] = MFMA_B16(a1, pe[1][1], O[dt][1]);
    }
    // normalize + store bf16 [T][B][E] — packed 8B store, no shfl
    const int bb = n >> 4, h = n & 15;
    #pragma unroll
    for (int nt = 0; nt < 2; nt++) {
        int t_g = t0 + w*32 + nt*16 + lc;
        #pragma unroll
        for (int dt = 0; dt < 4; dt++) {
            float v0 = O[dt][nt][0] * linv[nt];
            float v1 = O[dt][nt][1] * linv[nt];
            float v2 = O[dt][nt][2] * linv[nt];
            float v3 = O[dt][nt][3] * linv[nt];
            int e = h*64 + dt*16 + quad*4;
            *(uint2*)&aout[((size_t)t_g * B_ + bb) * E_ + e] =
                make_uint2(pk2(v0, v1), pk2(v2, v3));
        }
    }
}

// ---------------------------------------------------------------------------
// Output projection, bf16 MFMA GEMM, XCD swizzle, glds staging, dbuf.
// ---------------------------------------------------------------------------
__global__ __launch_bounds__(256, 3) void out_gemm(
    const unsigned short* __restrict__ A,
    const unsigned short* __restrict__ Wob, const unsigned short* __restrict__ bob,
    void* __restrict__ out, const int* __restrict__ flag)
{
    const bool f32m = (*flag != 0);
    const int bid = blockIdx.x;            // 256 blocks
    const int r_ = bid & 7, s_ = bid >> 3;
    const int g = r_ + 8 * (s_ >> 3);
    const int m0 = g * 128;
    const int e0 = (s_ & 7) * 128;

    const int tid = threadIdx.x, w = tid >> 6, lane = tid & 63;
    const int quad = lane >> 4, lc = lane & 15;
    const int wx = w & 1, wy = w >> 1;

    __shared__ unsigned short a_s[2][128 * 32];
    __shared__ unsigned short b_s[2][128 * 32];

    f4 acc[4][4];
    #pragma unroll
    for (int i = 0; i < 4; i++)
        #pragma unroll
        for (int j = 0; j < 4; j++) acc[i][j] = (f4){0.f, 0.f, 0.f, 0.f};

    const int gr = lane >> 2;
    const int gc = (lane & 3) ^ ((lane >> 2) & 3);
    const size_t aoff = (size_t)(m0 + w*32 + gr) * E_ + gc*8;
    const size_t boff = (size_t)(e0 + w*32 + gr) * E_ + gc*8;

    #pragma unroll
    for (int j = 0; j < 2; j++) {
        glds16(A   + aoff + (size_t)j*16*E_, &a_s[0][(w*128 + j*64) * 8]);
        glds16(Wob + boff + (size_t)j*16*E_, &b_s[0][(w*128 + j*64) * 8]);
    }
    __syncthreads();

    const int fcA = quad ^ (lc & 3);
    for (int k0 = 0; k0 < E_; k0 += 32) {
        const int cur = (k0 >> 5) & 1;
        if (k0 + 32 < E_) {
            #pragma unroll
            for (int j = 0; j < 2; j++) {
                glds16(A   + aoff + (size_t)j*16*E_ + k0 + 32, &a_s[cur^1][(w*128 + j*64) * 8]);
                glds16(Wob + boff + (size_t)j*16*E_ + k0 + 32, &b_s[cur^1][(w*128 + j*64) * 8]);
            }
        }
        s8b af[4], bfr[4];
        #pragma unroll
        for (int i = 0; i < 4; i++)
            af[i]  = *(const s8b*)&a_s[cur][((wy*64 + i*16 + lc)*4 + fcA) * 8];
        #pragma unroll
        for (int i = 0; i < 4; i++)
            bfr[i] = *(const s8b*)&b_s[cur][((wx*64 + i*16 + lc)*4 + fcA) * 8];
        #pragma unroll
        for (int ms = 0; ms < 4; ms++)
            #pragma unroll
            for (int ns = 0; ns < 4; ns++)
                acc[ms][ns] = MFMA_B16(af[ms], bfr[ns], acc[ms][ns]);
        __syncthreads();
    }

    float bias_v[4];
    #pragma unroll
    for (int ns = 0; ns < 4; ns++) bias_v[ns] = bu2f(bob[e0 + wx*64 + ns*16 + lc]);

    #pragma unroll
    for (int ms = 0; ms < 4; ms++)
        #pragma unroll
        for (int ns = 0; ns < 4; ns++)
            #pragma unroll
            for (int r2 = 0; r2 < 4; r2++) {
                float val = acc[ms][ns][r2] + bias_v[ns];
                size_t m = m0 + wy*64 + ms*16 + quad*4 + r2;
                int e = e0 + wx*64 + ns*16 + lc;
                if (f32m) {
                    ((float*)out)[m * E_ + e] = val;
                } else {
                    float nb = __shfl_xor(val, 1);
                    if (!(lane & 1))
                        *(unsigned int*)&((unsigned short*)out)[m * E_ + e] = pk2(val, nb);
                }
            }
}

extern "C" void kernel_launch(void* const* d_in, const int* in_sizes, int n_in,
                              void* d_out, int out_size, void* d_ws, size_t ws_size,
                              hipStream_t stream) {
    const void* x  = d_in[0];
    const void* Wq = d_in[1];  const void* bq = d_in[2];
    const void* Wk = d_in[3];  const void* bk = d_in[4];
    const void* Wv = d_in[5];  const void* bv = d_in[6];
    const void* Wo = d_in[7];  const void* bo = d_in[8];
    const void* rk = d_in[9];  const void* rv = d_in[10];

    int* flag = (int*)d_ws;
    const size_t HTD = (size_t)NH_ * T_ * D_;        // 4,194,304 elems
    unsigned short* qw = (unsigned short*)((char*)d_ws + 256);
    unsigned short* kw = qw + HTD;
    unsigned short* vw = kw + HTD;                   // V^T [N][D][T] bf16
    unsigned short* aw = vw + HTD;                   // [4096][1024] bf16 pre-Wo
    unsigned short* xw = aw + (size_t)M_ * E_;       // x as bf16 (8 MB)
    unsigned short* Ww = xw + (size_t)M_ * E_;       // Wq,Wk,Wv,Wo bf16 (8 MB)
    unsigned short* bw = Ww + (size_t)4 * E_ * E_;   // bq,bk,bv,bo bf16 (8 KB)
    // ws use: ~48 MB

    detect_dtype<<<1, 64, 0, stream>>>((const unsigned short*)x, flag);
    cvt_bf16<<<dim3((M_*E_/8 + 255)/256, 9), 256, 0, stream>>>(
        x, Wq, Wk, Wv, Wo, bq, bk, bv, bo, xw, Ww, bw, flag);
    qkv_gemm<<<dim3(768), 256, 0, stream>>>(xw, Ww, bw, qw, kw, vw);
    attn_mfma<<<dim3(NH_ * (T_/128)), 256, 0, stream>>>(qw, kw, vw, rk, rv, aw, flag);
    out_gemm<<<dim3(256), 256, 0, stream>>>(aw, Ww + (size_t)3*E_*E_, bw + 3*E_,
                                            d_out, flag);
}

// Round 15
// 232.617 us; speedup vs baseline: 1.0297x; 1.0297x over previous
//
#include <hip/hip_runtime.h>
#include <hip/hip_bf16.h>
#include <math.h>

#define T_   2048
#define B_   2
#define E_   1024
#define H_   16
#define D_   64
#define NH_  32
#define M_   4096

typedef __attribute__((ext_vector_type(8))) short s8b;   // 8 bf16 (4 VGPRs)
typedef __attribute__((ext_vector_type(4))) float f4;    // 4 f32 acc

#define MFMA_B16(a,b,c) __builtin_amdgcn_mfma_f32_16x16x32_bf16(a,b,c,0,0,0)
#define LOG2E 1.44269504088896f

__device__ __forceinline__ unsigned short f2bu(float f) {
    union { __hip_bfloat16 h; unsigned short u; } cv;
    cv.h = __float2bfloat16(f);
    return cv.u;
}
// fast bf16: round-half-up truncation (positive finite values) — 2 VALU ops
__device__ __forceinline__ unsigned short f2bu_fast(float f) {
    return (unsigned short)((__float_as_uint(f) + 0x8000u) >> 16);
}
__device__ __forceinline__ float bu2f(unsigned short u) {
    union { __hip_bfloat16 h; unsigned short u; } cv; cv.u = u;
    return __bfloat162float(cv.h);
}
__device__ __forceinline__ unsigned int pk2(float a, float b) {
    return (unsigned int)f2bu(a) | ((unsigned int)f2bu(b) << 16);
}
// pack two f32 -> packed bf16 pair with round-half-up (cheap)
__device__ __forceinline__ unsigned int pk2_fast(float a, float b) {
    return ((__float_as_uint(a) + 0x8000u) >> 16) |
           ((__float_as_uint(b) + 0x8000u) & 0xFFFF0000u);
}
// raw v_exp_f32 — exp2f() without fast-math expands to a denorm-guard
// sequence (~12 extra VALU ops); attention scores never reach denormals.
__device__ __forceinline__ float fexp2(float x) {
    return __builtin_amdgcn_exp2f(x);
}
__device__ __forceinline__ float ld1d(const void* p, size_t idx, bool f32) {
    return f32 ? ((const float*)p)[idx] : bu2f(((const unsigned short*)p)[idx]);
}
// sum across the 4 quads (lane bits 4-5)
__device__ __forceinline__ float qsumq(float v) {
    v += __shfl_xor(v, 16); v += __shfl_xor(v, 32);
    return v;
}
// async global->LDS, 16 B per lane (GEMMs only — attn uses register prefetch
// because its per-tile barrier drains vmcnt(0) and exposes the DMA latency)
__device__ __forceinline__ void glds16(const unsigned short* g, unsigned short* l) {
    __builtin_amdgcn_global_load_lds(
        (const __attribute__((address_space(1))) unsigned int*)g,
        (__attribute__((address_space(3))) unsigned int*)l, 16, 0, 0);
}
// dtype detect, wave-local (identical result in every wave): sample 64 u16
// words of x; bf16 data -> ~all exponent fields sane; f32-as-u16 -> ~half.
__device__ __forceinline__ bool detect_f32(const unsigned short* q16) {
    int e = (q16[threadIdx.x & 63] >> 7) & 0xFF;
    bool sane = (e == 0) || (e >= 97 && e <= 157);
    unsigned long long m = __ballot(sane);
    return __popcll(m) < 56;   // true = f32 inputs
}

// ---------------------------------------------------------------------------
// One-pass f32->bf16 conversion of x, Wq..Wo, bq..bo into ws. Also publishes
// the dtype flag (block (0,0) of the x region) for the attn/out kernels.
// ---------------------------------------------------------------------------
__global__ __launch_bounds__(256) void cvt_bf16(
    const void* __restrict__ x,
    const void* __restrict__ Wq, const void* __restrict__ Wk,
    const void* __restrict__ Wv, const void* __restrict__ Wo,
    const void* __restrict__ bq, const void* __restrict__ bk,
    const void* __restrict__ bv, const void* __restrict__ bo,
    unsigned short* __restrict__ xw, unsigned short* __restrict__ Ww,
    unsigned short* __restrict__ bw, int* __restrict__ flag)
{
    const bool f32m = detect_f32((const unsigned short*)x);
    if (blockIdx.x == 0 && blockIdx.y == 0 && threadIdx.x == 0)
        *flag = f32m ? 1 : 0;
    const int y = blockIdx.y;
    const void* src; unsigned short* dst; int n;
    if (y == 0)      { src = x; dst = xw; n = M_ * E_; }
    else if (y <= 4) {
        src = (y == 1) ? Wq : (y == 2) ? Wk : (y == 3) ? Wv : Wo;
        dst = Ww + (size_t)(y - 1) * E_ * E_; n = E_ * E_;
    } else {
        src = (y == 5) ? bq : (y == 6) ? bk : (y == 7) ? bv : bo;
        dst = bw + (size_t)(y - 5) * E_; n = E_;
    }
    int i = (blockIdx.x * 256 + threadIdx.x) * 8;
    if (i >= n) return;
    if (f32m) {
        const float* s = (const float*)src + i;
        float4 f0 = *(const float4*)s, f1 = *(const float4*)(s + 4);
        union { unsigned int d[4]; s8b v; } u;
        u.d[0] = pk2(f0.x, f0.y); u.d[1] = pk2(f0.z, f0.w);
        u.d[2] = pk2(f1.x, f1.y); u.d[3] = pk2(f1.z, f1.w);
        *(s8b*)(dst + i) = u.v;
    } else {
        *(s8b*)(dst + i) = *(const s8b*)((const unsigned short*)src + i);
    }
}

// ---------------------------------------------------------------------------
// QKV projection, bf16 MFMA GEMM, XCD swizzle, glds staging (xor-swizzled),
// double-buffered single-barrier. p==2 (V) is written TRANSPOSED [N][D][T].
// ---------------------------------------------------------------------------
__global__ __launch_bounds__(256, 3) void qkv_gemm(
    const unsigned short* __restrict__ xw, const unsigned short* __restrict__ Ww,
    const unsigned short* __restrict__ bw,
    unsigned short* __restrict__ qo, unsigned short* __restrict__ ko,
    unsigned short* __restrict__ vo)
{
    const int bid = blockIdx.x;            // 768 blocks
    const int r_ = bid & 7, s_ = bid >> 3;
    const int g = r_ + 8 * (s_ >> 3);      // group in [0,96): (m,p)
    const int e0 = (s_ & 7) * 128;
    const int m0 = (g & 31) * 128;
    const int p  = g >> 5;
    const unsigned short* W    = Ww + (size_t)p * E_ * E_;
    const unsigned short* bias = bw + (size_t)p * E_;
    const float scale = (p == 0) ? 0.125f * LOG2E : 1.0f;

    const int tid = threadIdx.x, w = tid >> 6, lane = tid & 63;
    const int quad = lane >> 4, lc = lane & 15;
    const int wx = w & 1, wy = w >> 1;

    __shared__ unsigned short a_s[2][128 * 32];
    __shared__ unsigned short b_s[2][128 * 32];

    f4 acc[4][4];
    #pragma unroll
    for (int i = 0; i < 4; i++)
        #pragma unroll
        for (int j = 0; j < 4; j++) acc[i][j] = (f4){0.f, 0.f, 0.f, 0.f};

    const int gr = lane >> 2;
    const int gc = (lane & 3) ^ ((lane >> 2) & 3);
    const size_t aoff = (size_t)(m0 + w*32 + gr) * E_ + gc*8;
    const size_t boff = (size_t)(e0 + w*32 + gr) * E_ + gc*8;

    #pragma unroll
    for (int j = 0; j < 2; j++) {
        glds16(xw + aoff + (size_t)j*16*E_, &a_s[0][(w*128 + j*64) * 8]);
        glds16(W  + boff + (size_t)j*16*E_, &b_s[0][(w*128 + j*64) * 8]);
    }
    __syncthreads();

    const int fcA = quad ^ (lc & 3);
    for (int k0 = 0; k0 < E_; k0 += 32) {
        const int cur = (k0 >> 5) & 1;
        if (k0 + 32 < E_) {
            #pragma unroll
            for (int j = 0; j < 2; j++) {
                glds16(xw + aoff + (size_t)j*16*E_ + k0 + 32, &a_s[cur^1][(w*128 + j*64) * 8]);
                glds16(W  + boff + (size_t)j*16*E_ + k0 + 32, &b_s[cur^1][(w*128 + j*64) * 8]);
            }
        }
        s8b af[4], bfr[4];
        #pragma unroll
        for (int i = 0; i < 4; i++)
            af[i]  = *(const s8b*)&a_s[cur][((wy*64 + i*16 + lc)*4 + fcA) * 8];
        #pragma unroll
        for (int i = 0; i < 4; i++)
            bfr[i] = *(const s8b*)&b_s[cur][((wx*64 + i*16 + lc)*4 + fcA) * 8];
        #pragma unroll
        for (int ms = 0; ms < 4; ms++)
            #pragma unroll
            for (int ns = 0; ns < 4; ns++)
                acc[ms][ns] = MFMA_B16(af[ms], bfr[ns], acc[ms][ns]);
        __syncthreads();
    }

    float bias_v[4];
    #pragma unroll
    for (int ns = 0; ns < 4; ns++) bias_v[ns] = bu2f(bias[e0 + wx*64 + ns*16 + lc]);

    if (p < 2) {
        #pragma unroll
        for (int ms = 0; ms < 4; ms++)
            #pragma unroll
            for (int ns = 0; ns < 4; ns++)
                #pragma unroll
                for (int r2 = 0; r2 < 4; r2++) {
                    float val = (acc[ms][ns][r2] + bias_v[ns]) * scale;
                    float nb = __shfl_xor(val, 1);
                    if (!(lane & 1)) {
                        int m = m0 + wy*64 + ms*16 + quad*4 + r2;
                        int t = m >> 1, bb = m & 1;
                        int e = e0 + wx*64 + ns*16 + lc;
                        int h = e >> 6, d = e & 63;
                        unsigned short* dst = (p == 0) ? qo : ko;
                        *(unsigned int*)&dst[(((size_t)(bb*H_ + h) * T_ + t) << 6) + d] = pk2(val, nb);
                    }
                }
    } else {
        // V transposed: vo[nh][d][t]
        #pragma unroll
        for (int ms = 0; ms < 4; ms++) {
            int t0v = (m0 + wy*64 + ms*16 + quad*4) >> 1;
            #pragma unroll
            for (int ns = 0; ns < 4; ns++) {
                int e = e0 + wx*64 + ns*16 + lc;
                int h = e >> 6, d = e & 63;
                float v0 = acc[ms][ns][0] + bias_v[ns];
                float v1 = acc[ms][ns][1] + bias_v[ns];
                float v2 = acc[ms][ns][2] + bias_v[ns];
                float v3 = acc[ms][ns][3] + bias_v[ns];
                *(unsigned int*)&vo[((size_t)h        * 64 + d) * T_ + t0v] = pk2(v0, v2);
                *(unsigned int*)&vo[((size_t)(H_ + h) * 64 + d) * T_ + t0v] = pk2(v1, v3);
            }
        }
    }
}

// ---------------------------------------------------------------------------
// Flash attention with Shaw bias — TRANSPOSED-S pipeline + raw v_exp_f32.
// R13 structure (best known): double-buffered K/V, register prefetch, ONE
// barrier per K-tile, __launch_bounds__(256,2) (grid = 512 = 2 blocks/CU,
// grid-capped — more blocks/CU is impossible without a grid restructure).
// ---------------------------------------------------------------------------
__global__ __launch_bounds__(256, 2) void attn_mfma(
    const unsigned short* __restrict__ q, const unsigned short* __restrict__ k,
    const unsigned short* __restrict__ v,
    const void* __restrict__ rk_t, const void* __restrict__ rv_t,
    unsigned short* __restrict__ aout, const int* __restrict__ flag)
{
    const bool f32m = (*flag != 0);
    const int bid = blockIdx.x;
    const int n = bid & 31, qt = bid >> 5;
    const int t0 = qt * 128;
    const int tid = threadIdx.x, w = tid >> 6, lane = tid & 63;
    const int quad = lane >> 4, lc = lane & 15;

    __shared__ unsigned short k_s[2][64 * 64];   // K[s][d] swizzled (buf0: rv^T later)
    __shared__ unsigned short v_s[2][64 * 64];   // V^T[d][s] swizzled
    __shared__ unsigned short p_s[4][32 * 72];   // per-wave P[t][s] / P_extra; rk staging
    __shared__ unsigned short qrk_s[128 * 36];   // qrk[t_local][r] bf16 (log2 dom.)
    __shared__ unsigned short diag16[128 * 33];  // e-values at |rel|<16, bf16
    __shared__ float st_L[128], st_R[128];

    const unsigned short* qn = q + ((size_t)n * T_ + t0) * D_;
    const unsigned short* kn = k + (size_t)n * T_ * D_;
    const unsigned short* vn = v + (size_t)n * D_ * T_;   // V^T [D][T]

    // Q fragments (B-operand for S^T)
    s8b qa[2][2];
    #pragma unroll
    for (int nt = 0; nt < 2; nt++)
        #pragma unroll
        for (int kf = 0; kf < 2; kf++)
            qa[nt][kf] = *(const s8b*)(qn + (size_t)(w*32 + nt*16 + lc) * D_ + kf*32 + quad*8);

    for (int i = tid; i < 128 * 33; i += 256) diag16[i] = 0;

    // stage rk (bf16, padded [48][72], rows>=33 zero) into p_s area
    unsigned int* rks = (unsigned int*)&p_s[0][0];
    for (int i = tid; i < 48 * 36; i += 256) {
        int r = i / 36, c2 = i % 36;
        unsigned int val = 0;
        if (r < 33 && c2 < 32)
            val = pk2(ld1d(rk_t, r*64 + 2*c2, f32m), ld1d(rk_t, r*64 + 2*c2 + 1, f32m));
        rks[i] = val;
    }
    __syncthreads();

    // qrk[t][r] = q[t] . rk[r] via MFMA (prologue-only)
    #pragma unroll
    for (int mt = 0; mt < 2; mt++)
        for (int nt = 0; nt < 3; nt++) {
            s8b b0 = *(const s8b*)((const unsigned short*)rks + (nt*16 + lc)*72 + quad*8);
            s8b b1 = *(const s8b*)((const unsigned short*)rks + (nt*16 + lc)*72 + 32 + quad*8);
            f4 a = (f4){0.f, 0.f, 0.f, 0.f};
            a = MFMA_B16(qa[mt][0], b0, a);
            a = MFMA_B16(qa[mt][1], b1, a);
            #pragma unroll
            for (int r = 0; r < 4; r++) {
                float nb = __shfl_xor(a[r], 1);
                int col = nt*16 + lc;
                if (!(lane & 1) && col < 34)
                    ((unsigned int*)qrk_s)[(w*32 + mt*16 + quad*4 + r)*18 + (col >> 1)] = pk2(a[r], nb);
            }
        }
    __syncthreads();   // rk staging (aliased with p_s) free after this

    // per-lane Shaw edge biases (t = w*32 + nt*16 + lc)
    float qLn[2], qRn[2];
    float L_p[2] = {0.f, 0.f}, R_p[2] = {0.f, 0.f};
    f4 O[4][2], lsN[2], lsL[2], lsR[2];
    #pragma unroll
    for (int nt = 0; nt < 2; nt++) {
        int row = w*32 + nt*16 + lc;
        qLn[nt] = bu2f(qrk_s[row*36 + 0]);
        qRn[nt] = bu2f(qrk_s[row*36 + 32]);
        lsN[nt] = (f4){0.f, 0.f, 0.f, 0.f};
        lsL[nt] = (f4){0.f, 0.f, 0.f, 0.f};
        lsR[nt] = (f4){0.f, 0.f, 0.f, 0.f};
        #pragma unroll
        for (int dt = 0; dt < 4; dt++) O[dt][nt] = (f4){0.f, 0.f, 0.f, 0.f};
    }
    const short ob = (short)0x3F80;   // bf16 1.0
    const s8b ones = { ob, ob, ob, ob, ob, ob, ob, ob };

    // staging mapping: row group w*16 + j*8 + grr, source chunk xor-swizzled
    const int grr = lane >> 3;
    const int gcc = (lane & 7) ^ grr;
    const size_t koff = (size_t)(w*16 + grr) * D_ + gcc*8;   // + (s0 + j*8)*D_
    const size_t voff = (size_t)(w*16 + grr) * T_ + gcc*8;   // + j*8*T_ + s0

    // tile-0 register prefetch + write buf 0
    s8b kr0 = *(const s8b*)(kn + koff);
    s8b kr1 = *(const s8b*)(kn + koff + 8*D_);
    s8b vr0 = *(const s8b*)(vn + voff);
    s8b vr1 = *(const s8b*)(vn + voff + (size_t)8*T_);
    *(s8b*)&k_s[0][(w*128 +      lane) * 8] = kr0;
    *(s8b*)&k_s[0][(w*128 + 64 + lane) * 8] = kr1;
    *(s8b*)&v_s[0][(w*128 +      lane) * 8] = vr0;
    *(s8b*)&v_s[0][(w*128 + 64 + lane) * 8] = vr1;
    __syncthreads();

    const int lc7 = lc & 7;
    for (int kt = 0; kt < 32; kt++) {
        const int s0 = kt * 64;
        const int cur = kt & 1;
        if (kt + 1 < 32) {   // issue next tile's global loads now
            kr0 = *(const s8b*)(kn + koff + (size_t)(s0 + 64)*D_);
            kr1 = *(const s8b*)(kn + koff + (size_t)(s0 + 72)*D_);
            vr0 = *(const s8b*)(vn + voff + s0 + 64);
            vr1 = *(const s8b*)(vn + voff + (size_t)8*T_ + s0 + 64);
        }

        const bool farL  = (s0 + 63 < t0 - 16);
        const bool farR  = (s0 > t0 + 143);
        const bool nearT = !farL && !farR;

        // K fragments (A-operand for S^T): K[s=st*16+lc][d]
        s8b ak[4][2];
        #pragma unroll
        for (int st = 0; st < 4; st++) {
            int row = st*16 + lc;
            ak[st][0] = *(const s8b*)&k_s[cur][(row*8 + (quad       ^ lc7)) * 8];
            ak[st][1] = *(const s8b*)&k_s[cur][(row*8 + ((4 + quad) ^ lc7)) * 8];
        }

        // S^T = K·Q^T (+ bias), exp2, pack b64 into P[t][s]
        #pragma unroll
        for (int st = 0; st < 4; st++)
            #pragma unroll
            for (int nt = 0; nt < 2; nt++) {
                f4 a;
                if (nearT) a = (f4){0.f, 0.f, 0.f, 0.f};
                else {
                    float qb = farL ? qLn[nt] : qRn[nt];
                    a = (f4){qb, qb, qb, qb};
                }
                a = MFMA_B16(ak[st][0], qa[nt][0], a);
                a = MFMA_B16(ak[st][1], qa[nt][1], a);
                unsigned int lo, hi;
                if (nearT) {
                    const int t_l = w*32 + nt*16 + lc;
                    const int sb  = s0 + st*16 + quad*4 - (t0 + t_l);
                    unsigned short eb[4];
                    #pragma unroll
                    for (int r = 0; r < 4; r++) {
                        int rel = sb + r;
                        int rc = rel < -16 ? -16 : (rel > 16 ? 16 : rel);
                        float e = fexp2(a[r] + bu2f(qrk_s[t_l*36 + rc + 16]));
                        eb[r] = f2bu_fast(e);
                        if (rel <= -16)      L_p[nt] += e;
                        else if (rel >= 16)  R_p[nt] += e;
                        else                 diag16[t_l*33 + rel + 15] = eb[r];
                    }
                    lo = (unsigned int)eb[0] | ((unsigned int)eb[1] << 16);
                    hi = (unsigned int)eb[2] | ((unsigned int)eb[3] << 16);
                } else {
                    lo = pk2_fast(fexp2(a[0]), fexp2(a[1]));
                    hi = pk2_fast(fexp2(a[2]), fexp2(a[3]));
                }
                *(uint2*)&p_s[w][(nt*16 + lc)*72 + st*16 + quad*4] = make_uint2(lo, hi);
            }

        // P fragments (B-operand): P[t=lc][s=quad*8+j]
        s8b pb[2][2];
        #pragma unroll
        for (int nt = 0; nt < 2; nt++) {
            pb[nt][0] = *(const s8b*)&p_s[w][(nt*16 + lc)*72 + quad*8];
            pb[nt][1] = *(const s8b*)&p_s[w][(nt*16 + lc)*72 + 32 + quad*8];
        }
        // column sums of P^T (= row sums of P) via ones-MFMA
        if (nearT) {
            #pragma unroll
            for (int nt = 0; nt < 2; nt++) {
                lsN[nt] = MFMA_B16(ones, pb[nt][0], lsN[nt]);
                lsN[nt] = MFMA_B16(ones, pb[nt][1], lsN[nt]);
            }
        } else if (farL) {
            #pragma unroll
            for (int nt = 0; nt < 2; nt++) {
                lsL[nt] = MFMA_B16(ones, pb[nt][0], lsL[nt]);
                lsL[nt] = MFMA_B16(ones, pb[nt][1], lsL[nt]);
            }
        } else {
            #pragma unroll
            for (int nt = 0; nt < 2; nt++) {
                lsR[nt] = MFMA_B16(ones, pb[nt][0], lsR[nt]);
                lsR[nt] = MFMA_B16(ones, pb[nt][1], lsR[nt]);
            }
        }
        // O^T += V^T · P^T
        #pragma unroll
        for (int dt = 0; dt < 4; dt++) {
            int row = dt*16 + lc;
            s8b a0 = *(const s8b*)&v_s[cur][(row*8 + (quad       ^ lc7)) * 8];
            s8b a1 = *(const s8b*)&v_s[cur][(row*8 + ((4 + quad) ^ lc7)) * 8];
            O[dt][0] = MFMA_B16(a0, pb[0][0], O[dt][0]);
            O[dt][0] = MFMA_B16(a1, pb[0][1], O[dt][0]);
            O[dt][1] = MFMA_B16(a0, pb[1][0], O[dt][1]);
            O[dt][1] = MFMA_B16(a1, pb[1][1], O[dt][1]);
        }

        if (kt + 1 < 32) {   // write prefetched tile to the other buffer
            *(s8b*)&k_s[cur ^ 1][(w*128 +      lane) * 8] = kr0;
            *(s8b*)&k_s[cur ^ 1][(w*128 + 64 + lane) * 8] = kr1;
            *(s8b*)&v_s[cur ^ 1][(w*128 +      lane) * 8] = vr0;
            *(s8b*)&v_s[cur ^ 1][(w*128 + 64 + lane) * 8] = vr1;
        }
        __syncthreads();
    }

    // ---- epilogue: totals, relpos-V via rv^T·P_extra^T, normalize, store ----
    float linv[2];
    #pragma unroll
    for (int nt = 0; nt < 2; nt++) {
        float l = lsN[nt][0] + lsL[nt][0] + lsR[nt][0];
        float L = lsL[nt][0] + qsumq(L_p[nt]);
        float R = lsR[nt][0] + qsumq(R_p[nt]);
        linv[nt] = 1.f / l;
        if (quad == 0) {
            int row = w*32 + nt*16 + lc;
            st_L[row] = L; st_R[row] = R;
        }
    }
    // stage rv TRANSPOSED into k_s[0] with the SAME xor swizzle (r>=33 zero)
    {
        unsigned int* rvs = (unsigned int*)&k_s[0][0];
        for (int i = tid; i < 64 * 32; i += 256) {
            int d = i >> 5, dwL = i & 31;
            int r0 = dwL * 2, r1 = r0 + 1;
            float x0 = (r0 < 33) ? ld1d(rv_t, (size_t)r0 * 64 + d, f32m) : 0.f;
            float x1 = (r1 < 33) ? ld1d(rv_t, (size_t)r1 * 64 + d, f32m) : 0.f;
            int phys = d * 32 + ((dwL >> 2) ^ (d & 7)) * 4 + (dwL & 3);
            rvs[phys] = pk2(x0, x1);
        }
    }
    __syncthreads();
    // build P_extra[32][64] bf16 in own wave region (cols 33..63 = 0)
    for (int j = 0; j < 32; j++) {
        int c = lane;
        int row = w*32 + j;
        unsigned short pv;
        if (c == 0)        pv = f2bu(st_L[row]);
        else if (c == 32)  pv = f2bu(st_R[row]);
        else if (c < 32)   pv = diag16[row*33 + c - 1];
        else               pv = 0;
        p_s[w][j*72 + c] = pv;
    }
    // O^T += rv^T · P_extra^T
    s8b pe[2][2];
    #pragma unroll
    for (int nt = 0; nt < 2; nt++) {
        pe[nt][0] = *(const s8b*)&p_s[w][(nt*16 + lc)*72 + quad*8];
        pe[nt][1] = *(const s8b*)&p_s[w][(nt*16 + lc)*72 + 32 + quad*8];
    }
    #pragma unroll
    for (int dt = 0; dt < 4; dt++) {
        int row = dt*16 + lc;
        s8b a0 = *(const s8b*)&k_s[0][(row*8 + (quad       ^ lc7)) * 8];
        s8b a1 = *(const s8b*)&k_s[0][(row*8 + ((4 + quad) ^ lc7)) * 8];
        O[dt][0] = MFMA_B16(a0, pe[0][0], O[dt][0]);
        O[dt][0] = MFMA_B16(a1, pe[0][1], O[dt][0]);
        O[dt][1] = MFMA_B16(a0, pe[1][0], O[dt][1]);
        O[dt][1] = MFMA_B16(a1, pe[1][1], O[dt][1]);
    }
    // normalize + store bf16 [T][B][E] — packed 8B store, no shfl
    const int bb = n >> 4, h = n & 15;
    #pragma unroll
    for (int nt = 0; nt < 2; nt++) {
        int t_g = t0 + w*32 + nt*16 + lc;
        #pragma unroll
        for (int dt = 0; dt < 4; dt++) {
            float v0 = O[dt][nt][0] * linv[nt];
            float v1 = O[dt][nt][1] * linv[nt];
            float v2 = O[dt][nt][2] * linv[nt];
            float v3 = O[dt][nt][3] * linv[nt];
            int e = h*64 + dt*16 + quad*4;
            *(uint2*)&aout[((size_t)t_g * B_ + bb) * E_ + e] =
                make_uint2(pk2(v0, v1), pk2(v2, v3));
        }
    }
}

// ---------------------------------------------------------------------------
// Output projection, bf16 MFMA GEMM, XCD swizzle, glds staging, dbuf.
// ---------------------------------------------------------------------------
__global__ __launch_bounds__(256, 3) void out_gemm(
    const unsigned short* __restrict__ A,
    const unsigned short* __restrict__ Wob, const unsigned short* __restrict__ bob,
    void* __restrict__ out, const int* __restrict__ flag)
{
    const bool f32m = (*flag != 0);
    const int bid = blockIdx.x;            // 256 blocks
    const int r_ = bid & 7, s_ = bid >> 3;
    const int g = r_ + 8 * (s_ >> 3);
    const int m0 = g * 128;
    const int e0 = (s_ & 7) * 128;

    const int tid = threadIdx.x, w = tid >> 6, lane = tid & 63;
    const int quad = lane >> 4, lc = lane & 15;
    const int wx = w & 1, wy = w >> 1;

    __shared__ unsigned short a_s[2][128 * 32];
    __shared__ unsigned short b_s[2][128 * 32];

    f4 acc[4][4];
    #pragma unroll
    for (int i = 0; i < 4; i++)
        #pragma unroll
        for (int j = 0; j < 4; j++) acc[i][j] = (f4){0.f, 0.f, 0.f, 0.f};

    const int gr = lane >> 2;
    const int gc = (lane & 3) ^ ((lane >> 2) & 3);
    const size_t aoff = (size_t)(m0 + w*32 + gr) * E_ + gc*8;
    const size_t boff = (size_t)(e0 + w*32 + gr) * E_ + gc*8;

    #pragma unroll
    for (int j = 0; j < 2; j++) {
        glds16(A   + aoff + (size_t)j*16*E_, &a_s[0][(w*128 + j*64) * 8]);
        glds16(Wob + boff + (size_t)j*16*E_, &b_s[0][(w*128 + j*64) * 8]);
    }
    __syncthreads();

    const int fcA = quad ^ (lc & 3);
    for (int k0 = 0; k0 < E_; k0 += 32) {
        const int cur = (k0 >> 5) & 1;
        if (k0 + 32 < E_) {
            #pragma unroll
            for (int j = 0; j < 2; j++) {
                glds16(A   + aoff + (size_t)j*16*E_ + k0 + 32, &a_s[cur^1][(w*128 + j*64) * 8]);
                glds16(Wob + boff + (size_t)j*16*E_ + k0 + 32, &b_s[cur^1][(w*128 + j*64) * 8]);
            }
        }
        s8b af[4], bfr[4];
        #pragma unroll
        for (int i = 0; i < 4; i++)
            af[i]  = *(const s8b*)&a_s[cur][((wy*64 + i*16 + lc)*4 + fcA) * 8];
        #pragma unroll
        for (int i = 0; i < 4; i++)
            bfr[i] = *(const s8b*)&b_s[cur][((wx*64 + i*16 + lc)*4 + fcA) * 8];
        #pragma unroll
        for (int ms = 0; ms < 4; ms++)
            #pragma unroll
            for (int ns = 0; ns < 4; ns++)
                acc[ms][ns] = MFMA_B16(af[ms], bfr[ns], acc[ms][ns]);
        __syncthreads();
    }

    float bias_v[4];
    #pragma unroll
    for (int ns = 0; ns < 4; ns++) bias_v[ns] = bu2f(bob[e0 + wx*64 + ns*16 + lc]);

    #pragma unroll
    for (int ms = 0; ms < 4; ms++)
        #pragma unroll
        for (int ns = 0; ns < 4; ns++)
            #pragma unroll
            for (int r2 = 0; r2 < 4; r2++) {
                float val = acc[ms][ns][r2] + bias_v[ns];
                size_t m = m0 + wy*64 + ms*16 + quad*4 + r2;
                int e = e0 + wx*64 + ns*16 + lc;
                if (f32m) {
                    ((float*)out)[m * E_ + e] = val;
                } else {
                    float nb = __shfl_xor(val, 1);
                    if (!(lane & 1))
                        *(unsigned int*)&((unsigned short*)out)[m * E_ + e] = pk2(val, nb);
                }
            }
}

extern "C" void kernel_launch(void* const* d_in, const int* in_sizes, int n_in,
                              void* d_out, int out_size, void* d_ws, size_t ws_size,
                              hipStream_t stream) {
    const void* x  = d_in[0];
    const void* Wq = d_in[1];  const void* bq = d_in[2];
    const void* Wk = d_in[3];  const void* bk = d_in[4];
    const void* Wv = d_in[5];  const void* bv = d_in[6];
    const void* Wo = d_in[7];  const void* bo = d_in[8];
    const void* rk = d_in[9];  const void* rv = d_in[10];

    int* flag = (int*)d_ws;
    const size_t HTD = (size_t)NH_ * T_ * D_;        // 4,194,304 elems
    unsigned short* qw = (unsigned short*)((char*)d_ws + 256);
    unsigned short* kw = qw + HTD;
    unsigned short* vw = kw + HTD;                   // V^T [N][D][T] bf16
    unsigned short* aw = vw + HTD;                   // [4096][1024] bf16 pre-Wo
    unsigned short* xw = aw + (size_t)M_ * E_;       // x as bf16 (8 MB)
    unsigned short* Ww = xw + (size_t)M_ * E_;       // Wq,Wk,Wv,Wo bf16 (8 MB)
    unsigned short* bw = Ww + (size_t)4 * E_ * E_;   // bq,bk,bv,bo bf16 (8 KB)
    // ws use: ~48 MB

    cvt_bf16<<<dim3((M_*E_/8 + 255)/256, 9), 256, 0, stream>>>(
        x, Wq, Wk, Wv, Wo, bq, bk, bv, bo, xw, Ww, bw, flag);
    qkv_gemm<<<dim3(768), 256, 0, stream>>>(xw, Ww, bw, qw, kw, vw);
    attn_mfma<<<dim3(NH_ * (T_/128)), 256, 0, stream>>>(qw, kw, vw, rk, rv, aw, flag);
    out_gemm<<<dim3(256), 256, 0, stream>>>(aw, Ww + (size_t)3*E_*E_, bw + 3*E_,
                                            d_out, flag);
}